// Round 2
// baseline (131.500 us; speedup 1.0000x reference)
//
#include <hip/hip_runtime.h>
#include <math.h>

#define NHW 676               // 26*26
#define NB 256
#define NCELLS (NB * NHW)     // 173056 cells
#define CPB 64                // cells per block = 1 wave
#define NBLK (NCELLS / CPB)   // 2704 blocks
#define NC 20                 // classes
#define NA 5                  // anchors

__device__ __forceinline__ float sigmoidf_(float x) {
    return 1.0f / (1.0f + __expf(-x));
}

// ---------------- kernel 1: per-cell losses -> per-block float4 partials ----------------
// One wave (64 threads) per block: minimal work quantum for CU load balance,
// 6.4 KB LDS (not the occupancy limiter), no cross-wave barrier.
__global__ __launch_bounds__(64) void yolo_loss_kernel(
    const float* __restrict__ pred,   // (B, 125, 26, 26)
    const float* __restrict__ tgt,    // (B, 26, 26, 25)
    float4* __restrict__ part)        // [NBLK] partials: box, conf, noobj, cls
{
    __shared__ __align__(16) float stgt[CPB * 25];   // 6.4 KB staged target

    const int tid = threadIdx.x;
    const int t0  = blockIdx.x * CPB;
    const int t   = t0 + tid;
    const int b   = t / NHW;
    const int hw  = t - b * NHW;
    const float* p = pred + (size_t)b * 125 * NHW + hw;   // channel stride NHW

    // ---- stage 64 cells' target, coalesced float4 (400 float4 / block) ----
    {
        const float4* g4 = (const float4*)(tgt + (size_t)t0 * 25);
        float4* s4 = (float4*)stgt;
        #pragma unroll
        for (int i = 0; i < 6; ++i) s4[i * 64 + tid] = g4[i * 64 + tid];
        if (tid < 16) s4[384 + tid] = g4[384 + tid];
    }

    // ---- 25 box/conf pred loads: NAMED SCALARS, no arrays -> no scratch ----
    // Issued before the LDS wait so VMEM overlaps the staging drain.
#define LD5(a) \
    float tc##a = p[((a)*25 + 20) * NHW]; \
    float tx##a = p[((a)*25 + 21) * NHW]; \
    float ty##a = p[((a)*25 + 22) * NHW]; \
    float tw##a = p[((a)*25 + 23) * NHW]; \
    float th##a = p[((a)*25 + 24) * NHW];
    LD5(0) LD5(1) LD5(2) LD5(3) LD5(4)
#undef LD5

    __syncthreads();   // single wave: compiles to a cheap waitcnt + barrier
    const float* tg = stgt + tid * 25;   // stride 25 mod 32 -> conflict-free

    const float gconf = tg[20];
    const float gx = tg[21], gy = tg[22], gw = tg[23], gh = tg[24];
    const float g_x1 = gx - gw * 0.5f, g_x2 = gx + gw * 0.5f;
    const float g_y1 = gy - gh * 0.5f, g_y2 = gy + gh * 0.5f;
    const float g_area = gw * gh;

    float best_iou = -1.0f;
    int   best_a = 0;
    float bx = 0.0f, by = 0.0f, bw = 0.0f, bh = 0.0f, btc = 0.0f;

#define IOU_STEP(a, AWc, AHc) { \
    float px = sigmoidf_(tx##a); \
    float py = sigmoidf_(ty##a); \
    float pw = __expf(tw##a) * (AWc); \
    float ph = __expf(th##a) * (AHc); \
    float iw = fminf(px + pw * 0.5f, g_x2) - fmaxf(px - pw * 0.5f, g_x1); \
    float ih = fminf(py + ph * 0.5f, g_y2) - fmaxf(py - ph * 0.5f, g_y1); \
    iw = fmaxf(iw, 0.0f); ih = fmaxf(ih, 0.0f); \
    float inter = iw * ih; \
    float uni = pw * ph + g_area - inter; \
    float iou = inter / (uni + 1e-10f); \
    if (iou > best_iou) { /* strict >: first max wins, matches jnp.argmax */ \
        best_iou = iou; best_a = (a); \
        bx = px; by = py; bw = pw; bh = ph; btc = tc##a; \
    } }
    IOU_STEP(0, 1.3221f,  1.73145f)
    IOU_STEP(1, 3.19275f, 4.00944f)
    IOU_STEP(2, 5.05587f, 8.09892f)
    IOU_STEP(3, 9.47112f, 4.84053f)
    IOU_STEP(4, 11.2364f, 10.0071f)
#undef IOU_STEP

    const float bconf = sigmoidf_(btc);

    float box_l = 0.0f, conf_l = 0.0f, noobj_l = 0.0f, cls_l = 0.0f;

    if (gconf != 0.0f) {
        float dx = bx - gx, dy = by - gy, dw = bw - gw, dh = bh - gh;
        box_l = dx * dx + dy * dy + dw * dw + dh * dh;
        float dc = bconf - gconf;
        conf_l = dc * dc;

        // ---- class NLL for best anchor only: 20 NAMED scalar loads ----
        const float* pc = p + best_a * 25 * NHW;
#define LDC(k) float l##k = pc[(k) * NHW];
        LDC(0) LDC(1) LDC(2) LDC(3) LDC(4) LDC(5) LDC(6) LDC(7) LDC(8) LDC(9)
        LDC(10) LDC(11) LDC(12) LDC(13) LDC(14) LDC(15) LDC(16) LDC(17) LDC(18) LDC(19)
#undef LDC
        float m = l0;
#define MAXC(k) m = fmaxf(m, l##k);
        MAXC(1) MAXC(2) MAXC(3) MAXC(4) MAXC(5) MAXC(6) MAXC(7) MAXC(8) MAXC(9)
        MAXC(10) MAXC(11) MAXC(12) MAXC(13) MAXC(14) MAXC(15) MAXC(16) MAXC(17) MAXC(18) MAXC(19)
#undef MAXC
        float s = 0.0f, lsel = 0.0f;
#define ACC(k) { s += __expf(l##k - m); lsel = fmaf(tg[k], l##k, lsel); }
        ACC(0) ACC(1) ACC(2) ACC(3) ACC(4) ACC(5) ACC(6) ACC(7) ACC(8) ACC(9)
        ACC(10) ACC(11) ACC(12) ACC(13) ACC(14) ACC(15) ACC(16) ACC(17) ACC(18) ACC(19)
#undef ACC
        cls_l = -(lsel - m - __logf(s));
    } else {
        noobj_l = bconf * bconf;
    }

    // ---- wave (64-lane) reduction; block == 1 wave so this is the whole block ----
    #pragma unroll
    for (int off = 32; off > 0; off >>= 1) {
        box_l   += __shfl_down(box_l,   off, 64);
        conf_l  += __shfl_down(conf_l,  off, 64);
        noobj_l += __shfl_down(noobj_l, off, 64);
        cls_l   += __shfl_down(cls_l,   off, 64);
    }

    if (tid == 0) {
        part[blockIdx.x] = make_float4(box_l, conf_l, noobj_l, cls_l);
    }
}

// ---------------- kernel 2: reduce NBLK float4 partials -> 4 scaled outputs ----------------
__global__ __launch_bounds__(256) void yolo_reduce_kernel(
    const float4* __restrict__ part,  // NBLK float4
    float* __restrict__ out)          // 4 floats
{
    __shared__ float sred[4][4];
    const int tid = threadIdx.x;

    float bx = 0.0f, cf = 0.0f, no = 0.0f, cl = 0.0f;
    for (int i = tid; i < NBLK; i += 256) {   // coalesced float4 reads
        float4 v = part[i];
        bx += v.x; cf += v.y; no += v.z; cl += v.w;
    }
    #pragma unroll
    for (int off = 32; off > 0; off >>= 1) {
        bx += __shfl_down(bx, off, 64);
        cf += __shfl_down(cf, off, 64);
        no += __shfl_down(no, off, 64);
        cl += __shfl_down(cl, off, 64);
    }
    const int wave = tid >> 6;
    const int lane = tid & 63;
    if (lane == 0) {
        sred[wave][0] = bx;
        sred[wave][1] = cf;
        sred[wave][2] = no;
        sred[wave][3] = cl;
    }
    __syncthreads();
    if (tid == 0) {
        float rb = sred[0][0] + sred[1][0] + sred[2][0] + sred[3][0];
        float rc = sred[0][1] + sred[1][1] + sred[2][1] + sred[3][1];
        float rn = sred[0][2] + sred[1][2] + sred[2][2] + sred[3][2];
        float rl = sred[0][3] + sred[1][3] + sred[2][3] + sred[3][3];
        out[0] = rb * (5.0f / 256.0f);
        out[1] = rc * (1.0f / 256.0f);
        out[2] = rn * (0.5f / 256.0f);
        out[3] = rl * (1.0f / 256.0f);
    }
}

extern "C" void kernel_launch(void* const* d_in, const int* in_sizes, int n_in,
                              void* d_out, int out_size, void* d_ws, size_t ws_size,
                              hipStream_t stream) {
    const float* pred = (const float*)d_in[0];
    const float* tgt  = (const float*)d_in[1];
    float* out = (float*)d_out;
    float4* part = (float4*)d_ws;

    hipLaunchKernelGGL(yolo_loss_kernel, dim3(NBLK), dim3(64), 0, stream,
                       pred, tgt, part);
    hipLaunchKernelGGL(yolo_reduce_kernel, dim3(1), dim3(256), 0, stream,
                       (const float4*)part, out);
}

// Round 3
// 129.896 us; speedup vs baseline: 1.0123x; 1.0123x over previous
//
#include <hip/hip_runtime.h>
#include <math.h>

#define NHW 676               // 26*26
#define NB 256
#define NCELLS (NB * NHW)     // 173056 = 676 blocks * 256 threads
#define NBLK 676
#define NC 20                 // classes
#define NA 5                  // anchors

__device__ __forceinline__ float sigmoidf_(float x) {
    return 1.0f / (1.0f + __expf(-x));
}

// ---------------- kernel 1: per-cell losses -> per-block float4 partials ----------------
__global__ __launch_bounds__(256) void yolo_loss_kernel(
    const float* __restrict__ pred,   // (B, 125, 26, 26)
    const float* __restrict__ tgt,    // (B, 26, 26, 25)
    float4* __restrict__ part)        // [NBLK] partials: box, conf, noobj, cls
{
    __shared__ __align__(16) float stgt[256 * 25];   // 25.6 KB staged target
    __shared__ float sred[4][4];

    const int tid = threadIdx.x;
    const int t0  = blockIdx.x << 8;
    const int t   = t0 + tid;
    const int b   = t / NHW;
    const int hw  = t - b * NHW;
    const float* p = pred + (size_t)b * 125 * NHW + hw;   // channel stride NHW

    // ---- stage target block, coalesced float4 (1600 float4 / block) ----
    {
        const float4* g4 = (const float4*)(tgt + (size_t)t0 * 25);
        float4* s4 = (float4*)stgt;
        #pragma unroll
        for (int i = 0; i < 6; ++i) s4[i * 256 + tid] = g4[i * 256 + tid];
        if (tid < 64) s4[1536 + tid] = g4[1536 + tid];
    }

    // ---- 25 box/conf pred loads: NAMED SCALARS, no arrays -> no scratch ----
#define LD5(a) \
    float tc##a = p[((a)*25 + 20) * NHW]; \
    float tx##a = p[((a)*25 + 21) * NHW]; \
    float ty##a = p[((a)*25 + 22) * NHW]; \
    float tw##a = p[((a)*25 + 23) * NHW]; \
    float th##a = p[((a)*25 + 24) * NHW];
    LD5(0) LD5(1) LD5(2) LD5(3) LD5(4)
#undef LD5

    __syncthreads();
    const float* tg = stgt + tid * 25;   // stride 25 mod 32 -> conflict-free

    const float gconf = tg[20];
    const float gx = tg[21], gy = tg[22], gw = tg[23], gh = tg[24];
    const float g_x1 = gx - gw * 0.5f, g_x2 = gx + gw * 0.5f;
    const float g_y1 = gy - gh * 0.5f, g_y2 = gy + gh * 0.5f;
    const float g_area = gw * gh;

    float best_iou = -1.0f;
    int   best_a = 0;
    float bx = 0.0f, by = 0.0f, bw = 0.0f, bh = 0.0f, btc = 0.0f;

#define IOU_STEP(a, AWc, AHc) { \
    float px = sigmoidf_(tx##a); \
    float py = sigmoidf_(ty##a); \
    float pw = __expf(tw##a) * (AWc); \
    float ph = __expf(th##a) * (AHc); \
    float iw = fminf(px + pw * 0.5f, g_x2) - fmaxf(px - pw * 0.5f, g_x1); \
    float ih = fminf(py + ph * 0.5f, g_y2) - fmaxf(py - ph * 0.5f, g_y1); \
    iw = fmaxf(iw, 0.0f); ih = fmaxf(ih, 0.0f); \
    float inter = iw * ih; \
    float uni = pw * ph + g_area - inter; \
    float iou = inter / (uni + 1e-10f); \
    if (iou > best_iou) { /* strict >: first max wins, matches jnp.argmax */ \
        best_iou = iou; best_a = (a); \
        bx = px; by = py; bw = pw; bh = ph; btc = tc##a; \
    } }
    IOU_STEP(0, 1.3221f,  1.73145f)
    IOU_STEP(1, 3.19275f, 4.00944f)
    IOU_STEP(2, 5.05587f, 8.09892f)
    IOU_STEP(3, 9.47112f, 4.84053f)
    IOU_STEP(4, 11.2364f, 10.0071f)
#undef IOU_STEP

    const float bconf = sigmoidf_(btc);

    float box_l = 0.0f, conf_l = 0.0f, noobj_l = 0.0f, cls_l = 0.0f;

    if (gconf != 0.0f) {
        float dx = bx - gx, dy = by - gy, dw = bw - gw, dh = bh - gh;
        box_l = dx * dx + dy * dy + dw * dw + dh * dh;
        float dc = bconf - gconf;
        conf_l = dc * dc;

        // ---- class NLL for best anchor only: 20 NAMED scalar loads ----
        const float* pc = p + best_a * 25 * NHW;
#define LDC(k) float l##k = pc[(k) * NHW];
        LDC(0) LDC(1) LDC(2) LDC(3) LDC(4) LDC(5) LDC(6) LDC(7) LDC(8) LDC(9)
        LDC(10) LDC(11) LDC(12) LDC(13) LDC(14) LDC(15) LDC(16) LDC(17) LDC(18) LDC(19)
#undef LDC
        float m = l0;
#define MAXC(k) m = fmaxf(m, l##k);
        MAXC(1) MAXC(2) MAXC(3) MAXC(4) MAXC(5) MAXC(6) MAXC(7) MAXC(8) MAXC(9)
        MAXC(10) MAXC(11) MAXC(12) MAXC(13) MAXC(14) MAXC(15) MAXC(16) MAXC(17) MAXC(18) MAXC(19)
#undef MAXC
        float s = 0.0f, lsel = 0.0f;
#define ACC(k) { s += __expf(l##k - m); lsel = fmaf(tg[k], l##k, lsel); }
        ACC(0) ACC(1) ACC(2) ACC(3) ACC(4) ACC(5) ACC(6) ACC(7) ACC(8) ACC(9)
        ACC(10) ACC(11) ACC(12) ACC(13) ACC(14) ACC(15) ACC(16) ACC(17) ACC(18) ACC(19)
#undef ACC
        cls_l = -(lsel - m - __logf(s));
    } else {
        noobj_l = bconf * bconf;
    }

    // ---- wave (64-lane) reduction ----
    #pragma unroll
    for (int off = 32; off > 0; off >>= 1) {
        box_l   += __shfl_down(box_l,   off, 64);
        conf_l  += __shfl_down(conf_l,  off, 64);
        noobj_l += __shfl_down(noobj_l, off, 64);
        cls_l   += __shfl_down(cls_l,   off, 64);
    }

    int wave = tid >> 6;
    int lane = tid & 63;
    if (lane == 0) {
        sred[wave][0] = box_l;
        sred[wave][1] = conf_l;
        sred[wave][2] = noobj_l;
        sred[wave][3] = cls_l;
    }
    __syncthreads();
    if (tid == 0) {
        float4 r;
        r.x = sred[0][0] + sred[1][0] + sred[2][0] + sred[3][0];
        r.y = sred[0][1] + sred[1][1] + sred[2][1] + sred[3][1];
        r.z = sred[0][2] + sred[1][2] + sred[2][2] + sred[3][2];
        r.w = sred[0][3] + sred[1][3] + sred[2][3] + sred[3][3];
        part[blockIdx.x] = r;   // plain store, zero contention
    }
}

// ---------------- kernel 2: reduce NBLK float4 partials -> 4 scaled outputs ----------------
__global__ __launch_bounds__(256) void yolo_reduce_kernel(
    const float* __restrict__ part,   // NBLK * 4 floats
    float* __restrict__ out)          // 4 floats
{
    const int wave = threadIdx.x >> 6;   // component: 0=box 1=conf 2=noobj 3=cls
    const int lane = threadIdx.x & 63;

    float s = 0.0f;
    for (int j = lane; j < NBLK; j += 64) {
        s += part[j * 4 + wave];
    }
    #pragma unroll
    for (int off = 32; off > 0; off >>= 1) {
        s += __shfl_down(s, off, 64);
    }
    if (lane == 0) {
        const float scale[4] = {5.0f / 256.0f, 1.0f / 256.0f, 0.5f / 256.0f, 1.0f / 256.0f};
        out[wave] = s * scale[wave];
    }
}

extern "C" void kernel_launch(void* const* d_in, const int* in_sizes, int n_in,
                              void* d_out, int out_size, void* d_ws, size_t ws_size,
                              hipStream_t stream) {
    const float* pred = (const float*)d_in[0];
    const float* tgt  = (const float*)d_in[1];
    float* out = (float*)d_out;
    float4* part = (float4*)d_ws;

    hipLaunchKernelGGL(yolo_loss_kernel, dim3(NCELLS / 256), dim3(256), 0, stream,
                       pred, tgt, part);
    hipLaunchKernelGGL(yolo_reduce_kernel, dim3(1), dim3(256), 0, stream,
                       (const float*)part, out);
}